// Round 12
// baseline (254.457 us; speedup 1.0000x reference)
//
#include <hip/hip_runtime.h>
#include <math.h>

#define N_NODES 20000
#define N_EDGES 320000
#define D1      256   // HEADS*HID
#define WCAP    128   // per-wave edge capacity (max deg ~45 for this input)
// k_prep block layout
#define XB      2500                 // x split (vec4): 2,560,000/4/256
#define W1B     (XB + 128)           // W1T: 32768/256
#define W2B     (W1B + 256)          // W2T: 65536/256
#define QB      W2B                  // q+bias: 1 block
#define DEGB    (QB + 1)             // deg histogram: 1250 blocks
#define WALLB   (DEGB + 1250)        // Wall^T: 32 blocks
#define NPREP   (WALLB + 32)

typedef __attribute__((ext_vector_type(8))) short    bf16x8;
typedef __attribute__((ext_vector_type(4))) float    f32x4;
typedef __attribute__((ext_vector_type(8))) unsigned short u16x8;
typedef __attribute__((ext_vector_type(4))) unsigned short u16x4;

__device__ inline float wred_sum(float v) {
#pragma unroll
  for (int o = 32; o > 0; o >>= 1) v += __shfl_xor(v, o, 64);
  return v;
}
__device__ inline float wred_max(float v) {
#pragma unroll
  for (int o = 32; o > 0; o >>= 1) v = fmaxf(v, __shfl_xor(v, o, 64));
  return v;
}

__device__ inline unsigned short f2b(float v) {
  unsigned u = __float_as_uint(v);
  unsigned r = (u + 0x7fffu + ((u >> 16) & 1u)) >> 16;
  return (unsigned short)r;
}
__device__ inline float b2f(unsigned short h) {
  return __uint_as_float(((unsigned)h) << 16);
}

// final rowptr value = raw block-local scan + block offset
__device__ inline int fr(const int* __restrict__ rp, const int* __restrict__ boff, int j) {
  return j ? rp[j] + boff[(j - 1) >> 10] : 0;
}

// ---- fused prep: x->bf16(vec4) | W1T | W2T | q+bias | deg | Wall^T ---------
__global__ __launch_bounds__(256) void k_prep(
    const float* __restrict__ x, unsigned short* __restrict__ xh,
    const float* __restrict__ W1, unsigned short* __restrict__ WT1h,
    unsigned short* __restrict__ WT1l,
    const float* __restrict__ W2, unsigned short* __restrict__ WT2h,
    unsigned short* __restrict__ WT2l,
    const float* __restrict__ We1, const float* __restrict__ ae1,
    const float* __restrict__ We2, const float* __restrict__ ae2,
    float* __restrict__ qb,
    const int* __restrict__ ei, int* __restrict__ deg,
    const float* __restrict__ Ww, const float* __restrict__ Wt,
    const float* __restrict__ Wa,
    const float* __restrict__ bw, const float* __restrict__ bt,
    const float* __restrict__ ba,
    unsigned short* __restrict__ WallTh, unsigned short* __restrict__ WallTl,
    float* __restrict__ biasAll) {
  int bid = blockIdx.x, t = threadIdx.x;
  if (bid < XB) {
    int i = (bid * 256 + t) * 4;              // vec4 x split
    float4 v = *(const float4*)&x[i];
    u16x4 o;
    o[0] = f2b(v.x); o[1] = f2b(v.y); o[2] = f2b(v.z); o[3] = f2b(v.w);
    *(u16x4*)&xh[i] = o;
  } else if (bid < W1B) {
    int i = (bid - XB) * 256 + t;             // 128*256
    int k = i >> 8, n = i & 255;
    float v = W1[i];
    unsigned short h = f2b(v);
    WT1h[n * 128 + k] = h;
    WT1l[n * 128 + k] = f2b(v - b2f(h));
  } else if (bid < W2B) {
    int i = (bid - W1B) * 256 + t;            // 256*256
    int k = i >> 8, n = i & 255;
    float v = W2[i];
    unsigned short h = f2b(v);
    WT2h[n * 256 + k] = h;
    WT2l[n * 256 + k] = f2b(v - b2f(h));
  } else if (bid == QB) {
    int lane = t & 63, w = t >> 6;
    const float* We = (w >> 1) ? We2 : We1;
    const float* ae = (w >> 1) ? ae2 : ae1;
    int c = w & 1;
#pragma unroll
    for (int h = 0; h < 4; h++) {
      float p = We[c * D1 + h * 64 + lane] * ae[h * 64 + lane];
      p = wred_sum(p);
      if (lane == 0) qb[(w >> 1) * 8 + c * 4 + h] = p;
    }
    if (t < 80) biasAll[t] = (t < 50) ? bw[t] : (t < 70) ? bt[t - 50] : ba[t - 70];
  } else if (bid < WALLB) {
    int e = (bid - DEGB) * 256 + t;           // deg histogram (int atomics)
    if (e < N_EDGES) atomicAdd(&deg[ei[N_EDGES + e]], 1);
  } else {
    int i = (bid - WALLB) * 256 + t;          // Wall^T [128][64], zero-padded
    int j = i >> 6, f = i & 63;
    float v = 0.f;
    if (j < 50)      v = Ww[f * 50 + j];
    else if (j < 70) v = Wt[f * 20 + (j - 50)];
    else if (j < 80) v = Wa[f * 10 + (j - 70)];
    unsigned short h = f2b(v);
    WallTh[j * 64 + f] = h;
    WallTl[j * 64 + f] = f2b(v - b2f(h));
  }
}

// ---- scan phase 1 ----------------------------------------------------------
__global__ __launch_bounds__(1024) void k_scan1(const int* __restrict__ deg,
                                                int* __restrict__ rowptr,
                                                int* __restrict__ bsum, int N) {
  __shared__ int wsum[16];
  int t = threadIdx.x, lane = t & 63, wid = t >> 6;
  int i = blockIdx.x * 1024 + t;
  int v = (i < N) ? deg[i] : 0;
  int sc = v;
#pragma unroll
  for (int o = 1; o < 64; o <<= 1) {
    int u = __shfl_up(sc, o, 64);
    if (lane >= o) sc += u;
  }
  if (lane == 63) wsum[wid] = sc;
  __syncthreads();
  if (wid == 0 && lane < 16) {
    int x = wsum[lane];
#pragma unroll
    for (int o = 1; o < 16; o <<= 1) {
      int u = __shfl_up(x, o, 64);
      if (lane >= o) x += u;
    }
    wsum[lane] = x;
  }
  __syncthreads();
  int off = wid ? wsum[wid - 1] : 0;
  if (i < N) rowptr[i + 1] = off + sc;   // block-local inclusive scan
  if (t == 0) bsum[blockIdx.x] = wsum[15];
}

__global__ void k_scan2(const int* __restrict__ bsum, int* __restrict__ boff, int nb) {
  int lane = threadIdx.x;  // 64 threads, nb <= 64
  int v = (lane < nb) ? bsum[lane] : 0;
  int sc = v;
#pragma unroll
  for (int o = 1; o < 64; o <<= 1) {
    int u = __shfl_up(sc, o, 64);
    if (lane >= o) sc += u;
  }
  if (lane < nb) boff[lane] = sc - v;
}

// ---- counting-sort scatter: ONE 16B packed entry per edge ------------------
__global__ void k_scatter(const int* __restrict__ ei, const float* __restrict__ ea,
                          const int* __restrict__ rowptr, const int* __restrict__ boff,
                          int* __restrict__ fill, int4* __restrict__ pkd) {
  int p = blockIdx.x * blockDim.x + threadIdx.x;
  if (p >= N_EDGES) return;
  int s = ei[p], d = ei[N_EDGES + p];
  float e0 = ea[p * 2], e1 = ea[p * 2 + 1];
  int pos = fr(rowptr, boff, d) + atomicAdd(&fill[d], 1);
  int4 pk;
  pk.x = s; pk.y = __float_as_int(e0); pk.z = __float_as_int(e1); pk.w = 0;
  pkd[pos] = pk;
}

// ---- 2-term split-bf16 MFMA GEMM + fused epilogue --------------------------
#define LDK 40  // 32 + 8 ushort pad
__global__ __launch_bounds__(256) void k_gemm_mfma(
    const unsigned short* __restrict__ Ah,
    const unsigned short* __restrict__ BTh, const unsigned short* __restrict__ BTl,
    unsigned short* __restrict__ Chi,
    const float* __restrict__ asw, const float* __restrict__ adw,
    float* __restrict__ asb, float* __restrict__ adb,
    int M, int K) {
  __shared__ unsigned short sAh[128 * LDK];
  __shared__ unsigned short sBh[128 * LDK], sBl[128 * LDK];
  int tid = threadIdx.x;
  int lane = tid & 63, wid = tid >> 6;
  int wr = wid >> 1, wc = wid & 1;
  int row0 = blockIdx.y * 128, col0 = blockIdx.x * 128;
  int aRow = wr * 64, bRow = wc * 64;

  f32x4 acc[4][4];
#pragma unroll
  for (int i = 0; i < 4; i++)
#pragma unroll
    for (int j = 0; j < 4; j++) acc[i][j] = (f32x4){0.f, 0.f, 0.f, 0.f};

  int c0i = tid * 2;
  int r0 = c0i >> 2, ko0 = (c0i & 3) * 8;
  int c1i = tid * 2 + 1;
  int r1 = c1i >> 2, ko1 = (c1i & 3) * 8;

  int q8 = (lane >> 4) * 8;
  int rsel = lane & 15;

  for (int k0 = 0; k0 < K; k0 += 32) {
    u16x8 z = {0, 0, 0, 0, 0, 0, 0, 0};
    int ga0 = row0 + r0, ga1 = row0 + r1;
    u16x8 vah0 = (ga0 < M) ? *(const u16x8*)&Ah[(size_t)ga0 * K + k0 + ko0] : z;
    u16x8 vah1 = (ga1 < M) ? *(const u16x8*)&Ah[(size_t)ga1 * K + k0 + ko1] : z;
    u16x8 vbh0 = *(const u16x8*)&BTh[(size_t)(col0 + r0) * K + k0 + ko0];
    u16x8 vbl0 = *(const u16x8*)&BTl[(size_t)(col0 + r0) * K + k0 + ko0];
    u16x8 vbh1 = *(const u16x8*)&BTh[(size_t)(col0 + r1) * K + k0 + ko1];
    u16x8 vbl1 = *(const u16x8*)&BTl[(size_t)(col0 + r1) * K + k0 + ko1];
    *(u16x8*)&sAh[r0 * LDK + ko0] = vah0;
    *(u16x8*)&sAh[r1 * LDK + ko1] = vah1;
    *(u16x8*)&sBh[r0 * LDK + ko0] = vbh0;
    *(u16x8*)&sBl[r0 * LDK + ko0] = vbl0;
    *(u16x8*)&sBh[r1 * LDK + ko1] = vbh1;
    *(u16x8*)&sBl[r1 * LDK + ko1] = vbl1;
    __syncthreads();

    bf16x8 fah[4], fbh[4], fbl[4];
#pragma unroll
    for (int i = 0; i < 4; i++) {
      int ar = aRow + i * 16 + rsel;
      int br = bRow + i * 16 + rsel;
      fah[i] = *(const bf16x8*)&sAh[ar * LDK + q8];
      fbh[i] = *(const bf16x8*)&sBh[br * LDK + q8];
      fbl[i] = *(const bf16x8*)&sBl[br * LDK + q8];
    }
#pragma unroll
    for (int i = 0; i < 4; i++)
#pragma unroll
      for (int j = 0; j < 4; j++) {
        acc[i][j] = __builtin_amdgcn_mfma_f32_16x16x32_bf16(fah[i], fbh[j], acc[i][j], 0, 0, 0);
        acc[i][j] = __builtin_amdgcn_mfma_f32_16x16x32_bf16(fah[i], fbl[j], acc[i][j], 0, 0, 0);
      }
    __syncthreads();
  }

  // ---- fused epilogue: C/D layout col=lane&15, row=(lane>>4)*4+reg ---------
  int rq = (lane >> 4) * 4;
  int head = (col0 + bRow) >> 6;   // this wave's 64 cols span exactly one head
  float sa[4], sd[4];
#pragma unroll
  for (int j = 0; j < 4; j++) {
    sa[j] = asw[head * 64 + j * 16 + rsel];
    sd[j] = adw[head * 64 + j * 16 + rsel];
  }
#pragma unroll
  for (int i = 0; i < 4; i++) {
#pragma unroll
    for (int j = 0; j < 4; j++) {
      int gcol = col0 + bRow + j * 16 + rsel;
#pragma unroll
      for (int r = 0; r < 4; r++) {
        int grow = row0 + aRow + i * 16 + rq + r;
        if (grow < M) Chi[(size_t)grow * D1 + gcol] = f2b(acc[i][j][r]);
      }
    }
#pragma unroll
    for (int r = 0; r < 4; r++) {
      float ps = 0.f, pd = 0.f;
#pragma unroll
      for (int j = 0; j < 4; j++) {
        ps = fmaf(acc[i][j][r], sa[j], ps);
        pd = fmaf(acc[i][j][r], sd[j], pd);
      }
#pragma unroll
      for (int o = 1; o < 16; o <<= 1) {
        ps += __shfl_xor(ps, o, 64);
        pd += __shfl_xor(pd, o, 64);
      }
      int grow = row0 + aRow + i * 16 + rq + r;
      if ((lane & 15) == 0 && grow < M) {
        asb[grow * 4 + head] = ps;
        adb[grow * 4 + head] = pd;
      }
    }
  }
}

// ---- 3-term MFMA head projection: [M x 64] @ [64 x 80] -> 3 outputs --------
__global__ __launch_bounds__(256) void k_heads_mfma(
    const unsigned short* __restrict__ Ah, const unsigned short* __restrict__ Al,
    const unsigned short* __restrict__ BTh, const unsigned short* __restrict__ BTl,
    const float* __restrict__ biasAll, float* __restrict__ out, int M) {
  __shared__ unsigned short sAh[128 * LDK], sAl[128 * LDK];
  __shared__ unsigned short sBh[128 * LDK], sBl[128 * LDK];
  const int K = 64;
  int tid = threadIdx.x;
  int lane = tid & 63, wid = tid >> 6;
  int wr = wid >> 1, wc = wid & 1;
  int row0 = blockIdx.x * 128;
  int aRow = wr * 64, bRow = wc * 64;

  f32x4 acc[4][4];
#pragma unroll
  for (int i = 0; i < 4; i++)
#pragma unroll
    for (int j = 0; j < 4; j++) acc[i][j] = (f32x4){0.f, 0.f, 0.f, 0.f};

  int c0i = tid * 2;
  int r0 = c0i >> 2, ko0 = (c0i & 3) * 8;
  int c1i = tid * 2 + 1;
  int r1 = c1i >> 2, ko1 = (c1i & 3) * 8;
  int q8 = (lane >> 4) * 8;
  int rsel = lane & 15;

  for (int k0 = 0; k0 < K; k0 += 32) {
    u16x8 z = {0, 0, 0, 0, 0, 0, 0, 0};
    int ga0 = row0 + r0, ga1 = row0 + r1;
    u16x8 vah0 = (ga0 < M) ? *(const u16x8*)&Ah[(size_t)ga0 * K + k0 + ko0] : z;
    u16x8 val0 = (ga0 < M) ? *(const u16x8*)&Al[(size_t)ga0 * K + k0 + ko0] : z;
    u16x8 vah1 = (ga1 < M) ? *(const u16x8*)&Ah[(size_t)ga1 * K + k0 + ko1] : z;
    u16x8 val1 = (ga1 < M) ? *(const u16x8*)&Al[(size_t)ga1 * K + k0 + ko1] : z;
    u16x8 vbh0 = *(const u16x8*)&BTh[(size_t)r0 * K + k0 + ko0];
    u16x8 vbl0 = *(const u16x8*)&BTl[(size_t)r0 * K + k0 + ko0];
    u16x8 vbh1 = *(const u16x8*)&BTh[(size_t)r1 * K + k0 + ko1];
    u16x8 vbl1 = *(const u16x8*)&BTl[(size_t)r1 * K + k0 + ko1];
    *(u16x8*)&sAh[r0 * LDK + ko0] = vah0;
    *(u16x8*)&sAl[r0 * LDK + ko0] = val0;
    *(u16x8*)&sAh[r1 * LDK + ko1] = vah1;
    *(u16x8*)&sAl[r1 * LDK + ko1] = val1;
    *(u16x8*)&sBh[r0 * LDK + ko0] = vbh0;
    *(u16x8*)&sBl[r0 * LDK + ko0] = vbl0;
    *(u16x8*)&sBh[r1 * LDK + ko1] = vbh1;
    *(u16x8*)&sBl[r1 * LDK + ko1] = vbl1;
    __syncthreads();

    bf16x8 fah[4], fal[4], fbh[4], fbl[4];
#pragma unroll
    for (int i = 0; i < 4; i++) {
      int ar = aRow + i * 16 + rsel;
      int br = bRow + i * 16 + rsel;
      fah[i] = *(const bf16x8*)&sAh[ar * LDK + q8];
      fal[i] = *(const bf16x8*)&sAl[ar * LDK + q8];
      fbh[i] = *(const bf16x8*)&sBh[br * LDK + q8];
      fbl[i] = *(const bf16x8*)&sBl[br * LDK + q8];
    }
#pragma unroll
    for (int i = 0; i < 4; i++)
#pragma unroll
      for (int j = 0; j < 4; j++) {
        acc[i][j] = __builtin_amdgcn_mfma_f32_16x16x32_bf16(fah[i], fbh[j], acc[i][j], 0, 0, 0);
        acc[i][j] = __builtin_amdgcn_mfma_f32_16x16x32_bf16(fah[i], fbl[j], acc[i][j], 0, 0, 0);
        acc[i][j] = __builtin_amdgcn_mfma_f32_16x16x32_bf16(fal[i], fbh[j], acc[i][j], 0, 0, 0);
      }
    __syncthreads();
  }

  // ---- scatter epilogue into the 3 concatenated outputs ----
  int rq = (lane >> 4) * 4;
#pragma unroll
  for (int j = 0; j < 4; j++) {
    int gcol = bRow + j * 16 + rsel;
    if (gcol < 80) {
      float bj = biasAll[gcol];
      float* op; int cols, jj;
      if (gcol < 50)      { op = out;                 cols = 50; jj = gcol; }
      else if (gcol < 70) { op = out + N_NODES * 50;  cols = 20; jj = gcol - 50; }
      else                { op = out + N_NODES * 70;  cols = 10; jj = gcol - 70; }
#pragma unroll
      for (int i = 0; i < 4; i++) {
#pragma unroll
        for (int r = 0; r < 4; r++) {
          int grow = row0 + aRow + i * 16 + rq + r;
          if (grow < M) op[(size_t)grow * cols + jj] = acc[i][j][r] + bj;
        }
      }
    }
  }
}

// ---- wave-per-node logits + softmax + full-row gather ----------------------
// CSR entry is one 16B int4 {src, ea0, ea1, 0}. Self-loop synthesized in-wave.
template <bool CONCAT>
__global__ __launch_bounds__(256) void k_aggregate(
    const unsigned short* __restrict__ feath,
    const int* __restrict__ rowptr, const int* __restrict__ boff,
    const int4* __restrict__ pkd,
    const float* __restrict__ asb, const float* __restrict__ adb,
    const float* __restrict__ q, const float* __restrict__ bias,
    unsigned short* __restrict__ outh,
    unsigned short* __restrict__ outf_h, unsigned short* __restrict__ outf_l) {
  __shared__ float slog[4][4][WCAP];
  __shared__ int   ssrc[4][WCAP];
  int t = threadIdx.x, lane = t & 63, w = t >> 6;
  int n = blockIdx.x * 4 + w;
  int b = fr(rowptr, boff, n);
  int e = fr(rowptr, boff, n + 1);
  int deg = e - b;           // real incoming edges (may be 0)

  float4 qv0 = *(const float4*)q;
  float4 qv1 = *(const float4*)(q + 4);
  float4 ad4 = *(const float4*)&adb[(size_t)n * 4];
  float4 asn = *(const float4*)&asb[(size_t)n * 4];

  if (deg <= WCAP) {
    // ---- logits: 2 register passes over real edges + ea sums ----
    float lv[2][4];
    float e0acc = 0.f, e1acc = 0.f;
#pragma unroll
    for (int p = 0; p < 2; p++) {
      int j = lane + p * 64;
      float l0 = -1e30f, l1 = -1e30f, l2 = -1e30f, l3 = -1e30f;
      if (j < deg) {
        int4 pk = pkd[b + j];
        int s = pk.x;
        float e0 = __int_as_float(pk.y), e1 = __int_as_float(pk.z);
        float4 as4 = *(const float4*)&asb[(size_t)s * 4];
        e0acc += e0; e1acc += e1;
        l0 = as4.x + ad4.x + e0 * qv0.x + e1 * qv1.x; l0 = (l0 > 0.f) ? l0 : 0.2f * l0;
        l1 = as4.y + ad4.y + e0 * qv0.y + e1 * qv1.y; l1 = (l1 > 0.f) ? l1 : 0.2f * l1;
        l2 = as4.z + ad4.z + e0 * qv0.z + e1 * qv1.z; l2 = (l2 > 0.f) ? l2 : 0.2f * l2;
        l3 = as4.w + ad4.w + e0 * qv0.w + e1 * qv1.w; l3 = (l3 > 0.f) ? l3 : 0.2f * l3;
        ssrc[w][j] = s;
      }
      lv[p][0] = l0; lv[p][1] = l1; lv[p][2] = l2; lv[p][3] = l3;
    }
    float dinv = 1.f / fmaxf((float)deg, 1.f);
    float e0m = wred_sum(e0acc) * dinv;
    float e1m = wred_sum(e1acc) * dinv;
    // ---- self-loop logits (wave-uniform) ----
    float ls[4];
    ls[0] = asn.x + ad4.x + e0m * qv0.x + e1m * qv1.x;
    ls[1] = asn.y + ad4.y + e0m * qv0.y + e1m * qv1.y;
    ls[2] = asn.z + ad4.z + e0m * qv0.z + e1m * qv1.z;
    ls[3] = asn.w + ad4.w + e0m * qv0.w + e1m * qv1.w;
#pragma unroll
    for (int h = 0; h < 4; h++) ls[h] = (ls[h] > 0.f) ? ls[h] : 0.2f * ls[h];
    // ---- in-wave softmax for all 4 heads (self edge included) ----
    float m[4], inv[4], wself[4];
#pragma unroll
    for (int h = 0; h < 4; h++) {
      float mm = fmaxf(wred_max(fmaxf(lv[0][h], lv[1][h])), ls[h]);
      float ss = wred_sum(__expf(lv[0][h] - mm) + __expf(lv[1][h] - mm))
                 + __expf(ls[h] - mm);
      m[h] = mm; inv[h] = 1.f / (ss + 1e-16f);
      wself[h] = __expf(ls[h] - mm) * inv[h];
    }
#pragma unroll
    for (int p = 0; p < 2; p++) {
      int j = lane + p * 64;
      if (j < deg) {
#pragma unroll
        for (int h = 0; h < 4; h++) slog[w][h][j] = __expf(lv[p][h] - m[h]) * inv[h];
      }
    }
    // wave-local producer/consumer: no barrier needed
    // ---- gather: all 256 cols per edge, 8 edges in flight ----
    int es = lane >> 5, cg = lane & 31, hh = cg >> 3;
    const unsigned short* fb = feath + cg * 8;
    float acc8[8] = {};
    int j0 = 0;
    for (; j0 + 8 <= deg; j0 += 8) {
      int e0 = j0 + es, e1 = j0 + 2 + es, e2 = j0 + 4 + es, e3 = j0 + 6 + es;
      int s0 = ssrc[w][e0], s1 = ssrc[w][e1], s2 = ssrc[w][e2], s3 = ssrc[w][e3];
      u16x8 f0 = *(const u16x8*)&fb[(size_t)s0 * D1];
      u16x8 f1 = *(const u16x8*)&fb[(size_t)s1 * D1];
      u16x8 f2 = *(const u16x8*)&fb[(size_t)s2 * D1];
      u16x8 f3 = *(const u16x8*)&fb[(size_t)s3 * D1];
      float w0 = slog[w][hh][e0], w1 = slog[w][hh][e1];
      float w2 = slog[w][hh][e2], w3 = slog[w][hh][e3];
#pragma unroll
      for (int k = 0; k < 8; k++) acc8[k] = fmaf(w0, b2f((unsigned short)f0[k]), acc8[k]);
#pragma unroll
      for (int k = 0; k < 8; k++) acc8[k] = fmaf(w1, b2f((unsigned short)f1[k]), acc8[k]);
#pragma unroll
      for (int k = 0; k < 8; k++) acc8[k] = fmaf(w2, b2f((unsigned short)f2[k]), acc8[k]);
#pragma unroll
      for (int k = 0; k < 8; k++) acc8[k] = fmaf(w3, b2f((unsigned short)f3[k]), acc8[k]);
    }
    for (; j0 < deg; j0 += 2) {          // exec-masked tail
      int e2 = j0 + es;
      if (e2 < deg) {
        float ww = slog[w][hh][e2];
        int s = ssrc[w][e2];
        u16x8 f8 = *(const u16x8*)&fb[(size_t)s * D1];
#pragma unroll
        for (int k = 0; k < 8; k++) acc8[k] = fmaf(ww, b2f((unsigned short)f8[k]), acc8[k]);
      }
    }
    if (es == 0) {                       // self-loop contribution (once)
      u16x8 fs = *(const u16x8*)&fb[(size_t)n * D1];
      float ws2 = wself[hh];
#pragma unroll
      for (int k = 0; k < 8; k++) acc8[k] = fmaf(ws2, b2f((unsigned short)fs[k]), acc8[k]);
    }
#pragma unroll
    for (int k = 0; k < 8; k++) acc8[k] += __shfl_xor(acc8[k], 32, 64);
    if (CONCAT) {
      if (es == 0) {
        u16x8 hi8;
#pragma unroll
        for (int k = 0; k < 8; k++) {
          float v2 = acc8[k] + bias[cg * 8 + k];
          v2 = (v2 > 0.f) ? v2 : (__expf(v2) - 1.f);
          hi8[k] = f2b(v2);
        }
        *(u16x8*)&outh[(size_t)n * D1 + cg * 8] = hi8;
      }
    } else {
      // head-mean: sum col-slices cg, cg^8, cg^16, cg^24
#pragma unroll
      for (int k = 0; k < 8; k++) {
        acc8[k] += __shfl_xor(acc8[k], 8, 64);
        acc8[k] += __shfl_xor(acc8[k], 16, 64);
      }
      if (es == 0 && cg < 8) {
        u16x8 hi8, lo8;
#pragma unroll
        for (int k = 0; k < 8; k++) {
          float v2 = acc8[k] * 0.25f + bias[cg * 8 + k];
          v2 = (v2 > 0.f) ? v2 : (__expf(v2) - 1.f);
          unsigned short hh2 = f2b(v2);
          hi8[k] = hh2;
          lo8[k] = f2b(v2 - b2f(hh2));
        }
        *(u16x8*)&outf_h[(size_t)n * 64 + cg * 8] = hi8;
        *(u16x8*)&outf_l[(size_t)n * 64 + cg * 8] = lo8;
      }
    }
  } else {
    // ---- fallback (deg > WCAP): streaming, wave-local, cold path ----
    float e0acc = 0.f, e1acc = 0.f;
    for (int p = b + lane; p < e; p += 64) {
      int4 pk = pkd[p];
      e0acc += __int_as_float(pk.y); e1acc += __int_as_float(pk.z);
    }
    float dinv = 1.f / fmaxf((float)deg, 1.f);
    float e0m = wred_sum(e0acc) * dinv;
    float e1m = wred_sum(e1acc) * dinv;
    float qh0[4] = {qv0.x, qv0.y, qv0.z, qv0.w};
    float qh1[4] = {qv1.x, qv1.y, qv1.z, qv1.w};
    float adh[4] = {ad4.x, ad4.y, ad4.z, ad4.w};
    float ash[4] = {asn.x, asn.y, asn.z, asn.w};
#pragma unroll
    for (int h = 0; h < 4; h++) {
      float q0 = qh0[h], q1 = qh1[h], adn = adh[h];
      float lself = ash[h] + adn + e0m * q0 + e1m * q1;
      lself = (lself > 0.f) ? lself : 0.2f * lself;
      float mm = -1e30f;
      for (int p = b + lane; p < e; p += 64) {
        int4 pk = pkd[p];
        float l = asb[pk.x * 4 + h] + adn + __int_as_float(pk.y) * q0
                  + __int_as_float(pk.z) * q1;
        l = (l > 0.f) ? l : 0.2f * l;
        mm = fmaxf(mm, l);
      }
      mm = fmaxf(wred_max(mm), lself);
      float s1 = 0.f;
      for (int p = b + lane; p < e; p += 64) {
        int4 pk = pkd[p];
        float l = asb[pk.x * 4 + h] + adn + __int_as_float(pk.y) * q0
                  + __int_as_float(pk.z) * q1;
        l = (l > 0.f) ? l : 0.2f * l;
        s1 += __expf(l - mm);
      }
      s1 = wred_sum(s1) + __expf(lself - mm);
      float inv = 1.f / (s1 + 1e-16f);
      float wself = __expf(lself - mm) * inv;
      const unsigned short* fb = feath + h * 64 + lane;
      float acc = wself * b2f(fb[(size_t)n * D1]);
      for (int c0 = b; c0 < e; c0 += 64) {
        int p = c0 + lane;
        float ww = 0.f; int si = 0;
        if (p < e) {
          int4 pk = pkd[p];
          float l = asb[pk.x * 4 + h] + adn + __int_as_float(pk.y) * q0
                    + __int_as_float(pk.z) * q1;
          l = (l > 0.f) ? l : 0.2f * l;
          ww = __expf(l - mm) * inv;
          si = pk.x;
        }
        slog[w][0][lane] = ww; ssrc[w][lane] = si;
        int cnt = min(64, e - c0);
        for (int j = 0; j < cnt; j++)
          acc = fmaf(slog[w][0][j], b2f(fb[(size_t)ssrc[w][j] * D1]), acc);
      }
      if (CONCAT) {
        float v = acc + bias[h * 64 + lane];
        v = (v > 0.f) ? v : (__expf(v) - 1.f);
        outh[(size_t)n * D1 + h * 64 + lane] = f2b(v);
      } else {
        slog[w][1][lane] = (h == 0) ? acc : slog[w][1][lane] + acc;
        if (h == 3) {
          float v = slog[w][1][lane] * 0.25f + bias[lane];
          v = (v > 0.f) ? v : (__expf(v) - 1.f);
          unsigned short hh2 = f2b(v);
          outf_h[(size_t)n * 64 + lane] = hh2;
          outf_l[(size_t)n * 64 + lane] = f2b(v - b2f(hh2));
        }
      }
    }
  }
}

extern "C" void kernel_launch(void* const* d_in, const int* in_sizes, int n_in,
                              void* d_out, int out_size, void* d_ws, size_t ws_size,
                              hipStream_t stream) {
  const float* x   = (const float*)d_in[0];
  const int*   ei  = (const int*)d_in[1];
  const float* ea  = (const float*)d_in[2];
  const float* W1  = (const float*)d_in[3];
  const float* We1 = (const float*)d_in[4];
  const float* as1 = (const float*)d_in[5];
  const float* ad1 = (const float*)d_in[6];
  const float* ae1 = (const float*)d_in[7];
  const float* b1  = (const float*)d_in[8];
  const float* W2  = (const float*)d_in[9];
  const float* We2 = (const float*)d_in[10];
  const float* as2 = (const float*)d_in[11];
  const float* ad2 = (const float*)d_in[12];
  const float* ae2 = (const float*)d_in[13];
  const float* b2  = (const float*)d_in[14];
  const float* Ww  = (const float*)d_in[15];
  const float* bw  = (const float*)d_in[16];
  const float* Wt  = (const float*)d_in[17];
  const float* bt  = (const float*)d_in[18];
  const float* Wa  = (const float*)d_in[19];
  const float* ba  = (const float*)d_in[20];
  float* out = (float*)d_out;

  char* ws = (char*)d_ws;
  size_t off = 0;
  auto alloc = [&](size_t bytes) {
    void* p = ws + off;
    off += (bytes + 255) & ~(size_t)255;
    return p;
  };
  unsigned short* Ah     = (unsigned short*)alloc((size_t)N_NODES * D1 * 2);  // GEMM bf16 out
  unsigned short* xh     = (unsigned short*)alloc((size_t)N_NODES * 128 * 2);
  unsigned short* Bfh    = (unsigned short*)alloc((size_t)N_NODES * D1 * 2);
  unsigned short* h2h    = (unsigned short*)alloc((size_t)N_NODES * 64 * 2);
  unsigned short* h2l    = (unsigned short*)alloc((size_t)N_NODES * 64 * 2);
  unsigned short* WT1h   = (unsigned short*)alloc((size_t)128 * 256 * 2);
  unsigned short* WT1l   = (unsigned short*)alloc((size_t)128 * 256 * 2);
  unsigned short* WT2h   = (unsigned short*)alloc((size_t)256 * 256 * 2);
  unsigned short* WT2l   = (unsigned short*)alloc((size_t)256 * 256 * 2);
  unsigned short* WallTh = (unsigned short*)alloc((size_t)128 * 64 * 2);
  unsigned short* WallTl = (unsigned short*)alloc((size_t)128 * 64 * 2);
  float*          biasAll= (float*)alloc(80 * 4);
  int4*  pkd     = (int4*)alloc((size_t)N_EDGES * 16);
  size_t zero_base = off;                       // deg/fill: one memset
  int*   deg     = (int*)alloc((size_t)N_NODES * 4);
  int*   fill    = (int*)alloc((size_t)N_NODES * 4);
  size_t zero_len = off - zero_base;
  int*   rowptr  = (int*)alloc((size_t)(N_NODES + 1) * 4);
  float* asb     = (float*)alloc((size_t)N_NODES * 4 * 4);
  float* adb     = (float*)alloc((size_t)N_NODES * 4 * 4);
  float* qb      = (float*)alloc(64);
  int*   bsum    = (int*)alloc(64 * 4);
  int*   boff    = (int*)alloc(64 * 4);

  hipMemsetAsync(ws + zero_base, 0, zero_len, stream);

  // ---- fused input conversions + deg histogram + Wall^T ----
  k_prep<<<NPREP, 256, 0, stream>>>(
      x, xh, W1, WT1h, WT1l, W2, WT2h, WT2l, We1, ae1, We2, ae2, qb, ei, deg,
      Ww, Wt, Wa, bw, bt, ba, WallTh, WallTl, biasAll);

  // ---- CSR build (real edges only; shared by both layers) ----
  const int NB = (N_NODES + 1023) / 1024;
  k_scan1<<<NB, 1024, 0, stream>>>(deg, rowptr, bsum, N_NODES);
  k_scan2<<<1, 64, 0, stream>>>(bsum, boff, NB);
  k_scatter<<<(N_EDGES + 255) / 256, 256, 0, stream>>>(ei, ea, rowptr, boff, fill, pkd);

  dim3 ggemm(2, (N_NODES + 127) / 128);

  // ---- layer 1 ----
  k_gemm_mfma<<<ggemm, 256, 0, stream>>>(xh, WT1h, WT1l, Ah, as1, ad1,
                                         asb, adb, N_NODES, 128);
  k_aggregate<true><<<N_NODES / 4, 256, 0, stream>>>(
      Ah, rowptr, boff, pkd, asb, adb, qb, b1, Bfh, nullptr, nullptr);

  // ---- layer 2 ----
  k_gemm_mfma<<<ggemm, 256, 0, stream>>>(Bfh, WT2h, WT2l, Ah, as2, ad2,
                                         asb, adb, N_NODES, 256);
  k_aggregate<false><<<N_NODES / 4, 256, 0, stream>>>(
      Ah, rowptr, boff, pkd, asb, adb, qb + 8, b2, nullptr, h2h, h2l);

  // ---- output heads (MFMA) ----
  k_heads_mfma<<<(N_NODES + 127) / 128, 256, 0, stream>>>(
      h2h, h2l, WallTh, WallTl, biasAll, out, N_NODES);
}